// Round 6
// baseline (435.426 us; speedup 1.0000x reference)
//
#include <hip/hip_runtime.h>
#include <hip/hip_bf16.h>
#include <string.h>

// CrossOp via bf16 MFMA (32x32x16) implicit-GEMM, w-split for occupancy.
// Block = (b, h, w-half): 1 output row x 64 px x all 64 co. Grid 1024 = 4 blocks/CU.
// Wave w: co-half (w&1)*32, px-group (w>>1)*32 (32 px). 9 MFMA k-steps (K=144).
// LDS: [3 rows][66 cols][16 ci pad->24] bf16, double-buffered (19 KB).
// XCD swizzle: xcd=bid&7 -> (b, w-half) fixed per XCD; h=bid>>3 -> h-halo L2-local.

typedef __attribute__((ext_vector_type(8))) short short8;
typedef __attribute__((ext_vector_type(16))) float f32x16;
typedef __attribute__((ext_vector_type(4))) unsigned int u32x4;

#define NEG_SLOPE 0.01f

constexpr int CIP   = 24;              // shorts per (row,col) ci slab (48 B)
constexpr int COLS  = 66;              // 64 px + 2 halo
constexpr int ROWP  = COLS * CIP;      // 1584 shorts
constexpr int BUFSH = 3 * ROWP;        // 4752 shorts = 9.5 KB per buffer

__device__ __forceinline__ short to_bf16s(float f) {
    unsigned u = __builtin_bit_cast(unsigned, f);
    u += 0x7fffu + ((u >> 16) & 1u);   // RNE
    return (short)(u >> 16);
}

__device__ __forceinline__ unsigned pack2(float a, float b) {
    __hip_bfloat162 t = __float22bfloat162_rn(float2{a, b});   // v_cvt_pk_bf16_f32
    unsigned u;
    memcpy(&u, &t, sizeof(u));
    return u;
}

__global__ __launch_bounds__(256, 2)
void crossop_mfma32(const float* __restrict__ xp, const float* __restrict__ yp,
                    const float* __restrict__ wp, const float* __restrict__ bp,
                    float* __restrict__ out)
{
    __shared__ __align__(16) short st[2][BUFSH];

    const int bid = blockIdx.x;            // 0..1023
    const int xcd = bid & 7;               // fixed (b, w-half) per XCD
    const int h   = bid >> 3;              // 0..127
    const int b   = xcd >> 1;
    const int w0  = (xcd & 1) << 6;

    const int tid  = threadIdx.x;
    const int lane = tid & 63;
    const int wid  = tid >> 6;
    const int l31  = lane & 31;
    const int hi   = lane >> 5;            // k-half / +4 co rows
    const int co0w = (wid & 1) << 5;       // wave's co base (0 or 32)
    const int pxg  = wid >> 1;             // wave's px-group (0 or 1)

    float* ntgt  = out;
    float* inter = out + (size_t)4 * 64 * 16384;

    // ---------------- zero LDS once (halo cols / OOB rows stay 0) ---------
    {
        u32x4 zz = {0, 0, 0, 0};
        u32x4* z = (u32x4*)&st[0][0];
        for (int i = tid; i < (2 * BUFSH * 2) / 16; i += 256) z[i] = zz;
    }

    // ---------------- staging mapping -------------------------------------
    const int  ch   = tid >> 7;            // ci half
    const int  wv   = tid & 127;           // LDS col; active if < COLS
    const bool sact = wv < COLS;
    const int  scol = w0 - 1 + wv;         // input col
    const bool scv  = sact && (unsigned)scol < 128u;
    float sr[3][8];

#define STAGE_ISSUE(SRC) do {                                                 \
    const float* _s = (SRC);                                                  \
    _Pragma("unroll")                                                         \
    for (int it = 0; it < 3; ++it) {                                          \
        int hh = h + it - 1;                                                  \
        bool v = scv && (unsigned)hh < 128u;                                  \
        const float* p = _s + (ptrdiff_t)(ch * 8) * 16384                     \
                            + (ptrdiff_t)hh * 128 + scol;                     \
        _Pragma("unroll")                                                     \
        for (int c = 0; c < 8; ++c)                                           \
            sr[it][c] = v ? p[(ptrdiff_t)c * 16384] : 0.f;                    \
    } } while (0)

#define STAGE_WRITE(BUF) do { if (sact) {                                     \
    _Pragma("unroll")                                                         \
    for (int it = 0; it < 3; ++it) {                                          \
        if ((unsigned)(h + it - 1) < 128u) {                                  \
            u32x4 vv;                                                         \
            _Pragma("unroll")                                                 \
            for (int c2 = 0; c2 < 4; ++c2)                                    \
                vv[c2] = pack2(sr[it][2 * c2], sr[it][2 * c2 + 1]);           \
            *(u32x4*)&(BUF)[it * ROWP + wv * CIP + ch * 8] = vv;              \
        }                                                                     \
    } } } while (0)

    // ---------------- persistent wy fragments (9 x short8 = 36 VGPR) ------
    short8 wy[9];
    #pragma unroll
    for (int sh = 0; sh < 9; ++sh) {
        #pragma unroll
        for (int j = 0; j < 8; ++j) {
            int ci = hi * 8 + j;           // k = (lane>>5)*8 + j within k-step
            wy[sh][j] = to_bf16s(wp[((co0w + l31) * 32 + 16 + ci) * 9 + sh]);
        }
    }

    // per-lane B column base: output local px p needs LDS cols p..p+2
    const int cb = (pxg * 32 + l31) * CIP + hi * 8;

    // ---------------- prologue: x -> buf0; ox = conv_x + bias -------------
    STAGE_ISSUE(xp + (size_t)b * 16 * 16384);
    STAGE_WRITE(st[0]);
    __syncthreads();

    f32x16 ox;
    #pragma unroll
    for (int r = 0; r < 16; ++r)
        ox[r] = bp[co0w + (r & 3) + 8 * (r >> 2) + 4 * hi];
    {
        const short* sb = st[0];
        #pragma unroll
        for (int sh = 0; sh < 9; ++sh) {
            short8 ax;
            #pragma unroll
            for (int j = 0; j < 8; ++j) {
                int ci = hi * 8 + j;
                ax[j] = to_bf16s(wp[((co0w + l31) * 32 + ci) * 9 + sh]);
            }
            const int off = (sh / 3) * ROWP + (sh % 3) * CIP;
            ox = __builtin_amdgcn_mfma_f32_32x32x16_bf16(ax, *(const short8*)&sb[cb + off], ox, 0, 0, 0);
        }
    }

    STAGE_ISSUE(yp + (size_t)(b * 32) * 16 * 16384);
    STAGE_WRITE(st[1]);
    __syncthreads();

    // ---------------- s-loop ----------------------------------------------
    f32x16 ms;
    #pragma unroll
    for (int r = 0; r < 16; ++r) ms[r] = 0.f;

    for (int s = 0; s < 32; ++s) {
        const short* sb = st[(s + 1) & 1];
        const bool pf = (s < 31);

        if (pf) STAGE_ISSUE(yp + (size_t)(b * 32 + s + 1) * 16 * 16384);

        {
            f32x16 acc = ox;
            #pragma unroll
            for (int sh = 0; sh < 9; ++sh) {
                const int off = (sh / 3) * ROWP + (sh % 3) * CIP;
                acc = __builtin_amdgcn_mfma_f32_32x32x16_bf16(wy[sh], *(const short8*)&sb[cb + off], acc, 0, 0, 0);
            }
            float* p0 = inter + ((size_t)(b * 32 + s) * 64 + co0w + 4 * hi) * 16384
                      + (size_t)h * 128 + w0 + pxg * 32 + l31;
            #pragma unroll
            for (int r = 0; r < 16; ++r) {
                float v = acc[r];
                v = v >= 0.f ? v : NEG_SLOPE * v;
                __builtin_nontemporal_store(v, p0 + (ptrdiff_t)((r & 3) + 8 * (r >> 2)) * 16384);
                ms[r] += v;
            }
        }

        if (pf) STAGE_WRITE(st[s & 1]);
        __syncthreads();
    }

    // ---------------- mean over Sy ----------------------------------------
    {
        float* p0 = ntgt + ((size_t)b * 64 + co0w + 4 * hi) * 16384
                  + (size_t)h * 128 + w0 + pxg * 32 + l31;
        #pragma unroll
        for (int r = 0; r < 16; ++r)
            __builtin_nontemporal_store(ms[r] * 0.03125f,
                                        p0 + (ptrdiff_t)((r & 3) + 8 * (r >> 2)) * 16384);
    }
#undef STAGE_ISSUE
#undef STAGE_WRITE
}

extern "C" void kernel_launch(void* const* d_in, const int* in_sizes, int n_in,
                              void* d_out, int out_size, void* d_ws, size_t ws_size,
                              hipStream_t stream) {
    const float* x    = (const float*)d_in[0];
    const float* y    = (const float*)d_in[1];
    const float* wgt  = (const float*)d_in[2];
    const float* bias = (const float*)d_in[3];
    float* out = (float*)d_out;

    crossop_mfma32<<<1024, 256, 0, stream>>>(x, y, wgt, bias, out);
}

// Round 7
// 175.280 us; speedup vs baseline: 2.4842x; 2.4842x over previous
//
#include <hip/hip_runtime.h>
#include <hip/hip_bf16.h>
#include <string.h>

// CrossOp via bf16 MFMA (32x32x16) implicit-GEMM.
// Block = (b, h): one output row, 128 px, all 64 co. Grid 512, 4 waves.
// Wave w: co-half (w&1)*32, px-groups (w>>1)*32 and (w>>1)*32+64 (32 px each).
// K = shift*16 + ci; 9 MFMA k-steps of 16 (one 3x3 shift each), no padding.
// LDS: [3 rows][130 cols][16 ci pad->24] bf16, double-buffered (37.4 KB).
// Loop uses raw s_barrier + lgkmcnt-only wait: interaction stores issued last
// and NOT drained at the barrier -> they complete during the next iteration's
// load-issue + MFMA phase (removes the __syncthreads vmcnt(0) store drain).

typedef __attribute__((ext_vector_type(8))) short short8;
typedef __attribute__((ext_vector_type(16))) float f32x16;
typedef __attribute__((ext_vector_type(4))) unsigned int u32x4;

#define NEG_SLOPE 0.01f

constexpr int CIP   = 24;              // shorts per (row,col) ci slab (48 B)
constexpr int COLS  = 130;             // 128 + 2 halo
constexpr int ROWP  = COLS * CIP;      // 3120 shorts
constexpr int BUFSH = 3 * ROWP;        // 9360 shorts = 18.7 KB per buffer

__device__ __forceinline__ short to_bf16s(float f) {
    unsigned u = __builtin_bit_cast(unsigned, f);
    u += 0x7fffu + ((u >> 16) & 1u);   // RNE
    return (short)(u >> 16);
}

__device__ __forceinline__ unsigned pack2(float a, float b) {
    __hip_bfloat162 t = __float22bfloat162_rn(float2{a, b});   // v_cvt_pk_bf16_f32
    unsigned u;
    memcpy(&u, &t, sizeof(u));
    return u;
}

__global__ __launch_bounds__(256, 2)
void crossop_mfma32(const float* __restrict__ xp, const float* __restrict__ yp,
                    const float* __restrict__ wp, const float* __restrict__ bp,
                    float* __restrict__ out)
{
    __shared__ __align__(16) short st[2][BUFSH];

    const int bid     = blockIdx.x;                     // 0..511
    const int logical = ((bid & 7) << 6) | (bid >> 3);  // XCD-chunked swizzle
    const int b       = logical >> 7;
    const int h       = logical & 127;

    const int tid  = threadIdx.x;
    const int lane = tid & 63;
    const int wid  = tid >> 6;
    const int l31  = lane & 31;
    const int hi   = lane >> 5;            // k-half / +4 co rows
    const int co0w = (wid & 1) << 5;       // wave's co base (0 or 32)
    const int pxg0 = wid >> 1;             // wave's first px-group (0 or 1)

    float* ntgt  = out;
    float* inter = out + (size_t)4 * 64 * 16384;

    // ---------------- zero LDS once (halo cols 0,129 + OOB rows stay 0) ---
    {
        u32x4 zz = {0, 0, 0, 0};
        u32x4* z = (u32x4*)&st[0][0];
        for (int i = tid; i < (2 * BUFSH * 2) / 16; i += 256) z[i] = zz;
    }

    // ---------------- staging mapping: all 256 threads active -------------
    const int ch = tid >> 7;               // ci half
    const int wv = tid & 127;              // input col w = wv, LDS col wv+1
    float sr[3][8];

#define STAGE_ISSUE(SRC) do {                                                 \
    const float* _s = (SRC);                                                  \
    _Pragma("unroll")                                                         \
    for (int it = 0; it < 3; ++it) {                                          \
        int hh = h + it - 1;                                                  \
        bool v = (unsigned)hh < 128u;                                         \
        const float* p = _s + (ptrdiff_t)(ch * 8) * 16384                     \
                            + (ptrdiff_t)hh * 128 + wv;                       \
        _Pragma("unroll")                                                     \
        for (int c = 0; c < 8; ++c)                                           \
            sr[it][c] = v ? p[(ptrdiff_t)c * 16384] : 0.f;                    \
    } } while (0)

#define STAGE_WRITE(BUF) do {                                                 \
    _Pragma("unroll")                                                         \
    for (int it = 0; it < 3; ++it) {                                          \
        if ((unsigned)(h + it - 1) < 128u) {                                  \
            u32x4 vv;                                                         \
            _Pragma("unroll")                                                 \
            for (int c2 = 0; c2 < 4; ++c2)                                    \
                vv[c2] = pack2(sr[it][2 * c2], sr[it][2 * c2 + 1]);           \
            *(u32x4*)&(BUF)[it * ROWP + (wv + 1) * CIP + ch * 8] = vv;        \
        }                                                                     \
    } } while (0)

    // ---------------- persistent wy fragments (9 x short8 = 36 VGPR) ------
    short8 wy[9];
    #pragma unroll
    for (int sh = 0; sh < 9; ++sh) {
        #pragma unroll
        for (int j = 0; j < 8; ++j) {
            int ci = hi * 8 + j;           // k = (lane>>5)*8 + j within k-step
            wy[sh][j] = to_bf16s(wp[((co0w + l31) * 32 + 16 + ci) * 9 + sh]);
        }
    }

    // per-lane B column bases (shorts) for the two px groups
    const int cb0 = (pxg0 * 32 + l31) * CIP + hi * 8;
    const int cb1 = (pxg0 * 32 + 64 + l31) * CIP + hi * 8;

    // ---------------- prologue: x -> buf0; ox = conv_x + bias -------------
    STAGE_ISSUE(xp + (size_t)b * 16 * 16384);
    STAGE_WRITE(st[0]);
    __syncthreads();

    f32x16 ox0, ox1;
    #pragma unroll
    for (int r = 0; r < 16; ++r) {
        float bv = bp[co0w + (r & 3) + 8 * (r >> 2) + 4 * hi];
        ox0[r] = bv; ox1[r] = bv;
    }
    {
        const short* sb = st[0];
        #pragma unroll
        for (int sh = 0; sh < 9; ++sh) {
            short8 ax;
            #pragma unroll
            for (int j = 0; j < 8; ++j) {
                int ci = hi * 8 + j;
                ax[j] = to_bf16s(wp[((co0w + l31) * 32 + ci) * 9 + sh]);
            }
            const int off = (sh / 3) * ROWP + (sh % 3) * CIP;
            ox0 = __builtin_amdgcn_mfma_f32_32x32x16_bf16(ax, *(const short8*)&sb[cb0 + off], ox0, 0, 0, 0);
            ox1 = __builtin_amdgcn_mfma_f32_32x32x16_bf16(ax, *(const short8*)&sb[cb1 + off], ox1, 0, 0, 0);
        }
    }

    STAGE_ISSUE(yp + (size_t)(b * 32) * 16 * 16384);
    STAGE_WRITE(st[1]);
    __syncthreads();

    // ---------------- s-loop ----------------------------------------------
    f32x16 ms0, ms1;
    #pragma unroll
    for (int r = 0; r < 16; ++r) { ms0[r] = 0.f; ms1[r] = 0.f; }

    for (int s = 0; s < 32; ++s) {
        const short* sb = st[(s + 1) & 1];
        const bool pf = (s < 31);

        // 1) issue next-tile global loads (latency covered by MFMA phase)
        if (pf) STAGE_ISSUE(yp + (size_t)(b * 32 + s + 1) * 16 * 16384);

        // 2) MFMA phase: both px groups, accumulators stay in registers
        f32x16 acc0 = ox0, acc1 = ox1;
        #pragma unroll
        for (int sh = 0; sh < 9; ++sh) {
            const int off = (sh / 3) * ROWP + (sh % 3) * CIP;
            acc0 = __builtin_amdgcn_mfma_f32_32x32x16_bf16(wy[sh], *(const short8*)&sb[cb0 + off], acc0, 0, 0, 0);
            acc1 = __builtin_amdgcn_mfma_f32_32x32x16_bf16(wy[sh], *(const short8*)&sb[cb1 + off], acc1, 0, 0, 0);
        }

        // 3) pack + ds_write next tile (vmcnt waits only on the 24 loads;
        //    prev iteration's stores have had a full phase to drain)
        if (pf) STAGE_WRITE(st[s & 1]);

        // 4) leaky + NT stores issued LAST — not drained at the barrier
        {
            const size_t sbase = ((size_t)(b * 32 + s) * 64 + co0w + 4 * hi) * 16384
                               + (size_t)h * 128;
            float* p0 = inter + sbase + pxg0 * 32 + l31;
            float* p1 = inter + sbase + pxg0 * 32 + 64 + l31;
            #pragma unroll
            for (int r = 0; r < 16; ++r) {
                const ptrdiff_t off = (ptrdiff_t)((r & 3) + 8 * (r >> 2)) * 16384;
                float v0 = acc0[r];
                v0 = v0 >= 0.f ? v0 : NEG_SLOPE * v0;
                __builtin_nontemporal_store(v0, p0 + off);
                ms0[r] += v0;
                float v1 = acc1[r];
                v1 = v1 >= 0.f ? v1 : NEG_SLOPE * v1;
                __builtin_nontemporal_store(v1, p1 + off);
                ms1[r] += v1;
            }
        }

        // 5) LDS-only barrier: wait ds ops, NOT the global stores
        asm volatile("s_waitcnt lgkmcnt(0)" ::: "memory");
        __builtin_amdgcn_s_barrier();
        asm volatile("" ::: "memory");
    }

    // ---------------- mean over Sy ----------------------------------------
    {
        const size_t nb = ((size_t)b * 64 + co0w + 4 * hi) * 16384 + (size_t)h * 128;
        float* p0 = ntgt + nb + pxg0 * 32 + l31;
        float* p1 = ntgt + nb + pxg0 * 32 + 64 + l31;
        #pragma unroll
        for (int r = 0; r < 16; ++r) {
            const ptrdiff_t off = (ptrdiff_t)((r & 3) + 8 * (r >> 2)) * 16384;
            __builtin_nontemporal_store(ms0[r] * 0.03125f, p0 + off);
            __builtin_nontemporal_store(ms1[r] * 0.03125f, p1 + off);
        }
    }
#undef STAGE_ISSUE
#undef STAGE_WRITE
}

extern "C" void kernel_launch(void* const* d_in, const int* in_sizes, int n_in,
                              void* d_out, int out_size, void* d_ws, size_t ws_size,
                              hipStream_t stream) {
    const float* x    = (const float*)d_in[0];
    const float* y    = (const float*)d_in[1];
    const float* wgt  = (const float*)d_in[2];
    const float* bias = (const float*)d_in[3];
    float* out = (float*)d_out;

    crossop_mfma32<<<512, 256, 0, stream>>>(x, y, wgt, bias, out);
}

// Round 8
// 154.120 us; speedup vs baseline: 2.8252x; 1.1373x over previous
//
#include <hip/hip_runtime.h>
#include <hip/hip_bf16.h>
#include <string.h>

// CrossOp via bf16 MFMA (32x32x16) implicit-GEMM.
// Block = (b, h): one output row, 128 px, all 64 co. Grid 512, EIGHT waves.
// Wave w: co-half (w&1)*32, px-group (w>>1)*32 (32 px). 9 MFMA k-steps (K=144).
// Same tile/traffic as the 4-wave version, 2x waves for latency hiding:
// 2 blocks/CU x 8 waves = 4 waves/SIMD (needs VGPR<=128 via launch_bounds(512,4)).
// LDS: [3 rows][130 cols][16 ci pad->24] bf16, double-buffered (37.4 KB).
// Stores issued last + lgkmcnt-only barrier (stores drain across next phase).

typedef __attribute__((ext_vector_type(8))) short short8;
typedef __attribute__((ext_vector_type(16))) float f32x16;
typedef __attribute__((ext_vector_type(2))) unsigned int u32x2;
typedef __attribute__((ext_vector_type(4))) unsigned int u32x4;

#define NEG_SLOPE 0.01f

constexpr int CIP   = 24;              // shorts per (row,col) ci slab (48 B)
constexpr int COLS  = 130;             // 128 + 2 halo
constexpr int ROWP  = COLS * CIP;      // 3120 shorts
constexpr int BUFSH = 3 * ROWP;        // 9360 shorts = 18.7 KB per buffer

__device__ __forceinline__ short to_bf16s(float f) {
    unsigned u = __builtin_bit_cast(unsigned, f);
    u += 0x7fffu + ((u >> 16) & 1u);   // RNE
    return (short)(u >> 16);
}

__device__ __forceinline__ unsigned pack2(float a, float b) {
    __hip_bfloat162 t = __float22bfloat162_rn(float2{a, b});   // v_cvt_pk_bf16_f32
    unsigned u;
    memcpy(&u, &t, sizeof(u));
    return u;
}

__global__ __launch_bounds__(512, 4)
void crossop_mfma32(const float* __restrict__ xp, const float* __restrict__ yp,
                    const float* __restrict__ wp, const float* __restrict__ bp,
                    float* __restrict__ out)
{
    __shared__ __align__(16) short st[2][BUFSH];

    const int bid     = blockIdx.x;                     // 0..511
    const int logical = ((bid & 7) << 6) | (bid >> 3);  // XCD-chunked swizzle
    const int b       = logical >> 7;
    const int h       = logical & 127;

    const int tid  = threadIdx.x;
    const int lane = tid & 63;
    const int wid  = tid >> 6;             // 0..7
    const int l31  = lane & 31;
    const int hi   = lane >> 5;            // k-half / +4 co rows
    const int co0w = (wid & 1) << 5;       // wave's co base (0 or 32)
    const int pxg  = wid >> 1;             // wave's px-group (0..3)

    float* ntgt  = out;
    float* inter = out + (size_t)4 * 64 * 16384;

    // ---------------- zero LDS once (halo cols 0,129 + OOB rows stay 0) ---
    {
        u32x4 zz = {0, 0, 0, 0};
        u32x4* z = (u32x4*)&st[0][0];
        for (int i = tid; i < (2 * BUFSH * 2) / 16; i += 512) z[i] = zz;
    }

    // ---------------- staging mapping: 512 threads, 12 values each --------
    const int ch = tid >> 7;               // ci quarter (0..3) -> ci 4*ch..4*ch+3
    const int wv = tid & 127;              // input col w = wv, LDS col wv+1
    float sr[3][4];

#define STAGE_ISSUE(SRC) do {                                                 \
    const float* _s = (SRC);                                                  \
    _Pragma("unroll")                                                         \
    for (int it = 0; it < 3; ++it) {                                          \
        int hh = h + it - 1;                                                  \
        bool v = (unsigned)hh < 128u;                                         \
        const float* p = _s + (ptrdiff_t)(ch * 4) * 16384                     \
                            + (ptrdiff_t)hh * 128 + wv;                       \
        _Pragma("unroll")                                                     \
        for (int c = 0; c < 4; ++c)                                           \
            sr[it][c] = v ? p[(ptrdiff_t)c * 16384] : 0.f;                    \
    } } while (0)

#define STAGE_WRITE(BUF) do {                                                 \
    _Pragma("unroll")                                                         \
    for (int it = 0; it < 3; ++it) {                                          \
        if ((unsigned)(h + it - 1) < 128u) {                                  \
            u32x2 vv;                                                         \
            vv[0] = pack2(sr[it][0], sr[it][1]);                              \
            vv[1] = pack2(sr[it][2], sr[it][3]);                              \
            *(u32x2*)&(BUF)[it * ROWP + (wv + 1) * CIP + ch * 4] = vv;        \
        }                                                                     \
    } } while (0)

    // ---------------- persistent wy fragments (9 x short8 = 36 VGPR) ------
    short8 wy[9];
    #pragma unroll
    for (int sh = 0; sh < 9; ++sh) {
        #pragma unroll
        for (int j = 0; j < 8; ++j) {
            int ci = hi * 8 + j;           // k = (lane>>5)*8 + j within k-step
            wy[sh][j] = to_bf16s(wp[((co0w + l31) * 32 + 16 + ci) * 9 + sh]);
        }
    }

    // per-lane B column base (shorts) for this wave's px group
    const int cb = (pxg * 32 + l31) * CIP + hi * 8;

    // ---------------- prologue: x -> buf0; ox = conv_x + bias -------------
    STAGE_ISSUE(xp + (size_t)b * 16 * 16384);
    STAGE_WRITE(st[0]);
    __syncthreads();

    f32x16 ox;
    #pragma unroll
    for (int r = 0; r < 16; ++r)
        ox[r] = bp[co0w + (r & 3) + 8 * (r >> 2) + 4 * hi];
    {
        const short* sb = st[0];
        #pragma unroll
        for (int sh = 0; sh < 9; ++sh) {
            short8 ax;
            #pragma unroll
            for (int j = 0; j < 8; ++j) {
                int ci = hi * 8 + j;
                ax[j] = to_bf16s(wp[((co0w + l31) * 32 + ci) * 9 + sh]);
            }
            const int off = (sh / 3) * ROWP + (sh % 3) * CIP;
            ox = __builtin_amdgcn_mfma_f32_32x32x16_bf16(ax, *(const short8*)&sb[cb + off], ox, 0, 0, 0);
        }
    }

    STAGE_ISSUE(yp + (size_t)(b * 32) * 16 * 16384);
    STAGE_WRITE(st[1]);
    __syncthreads();

    // ---------------- s-loop ----------------------------------------------
    f32x16 ms;
    #pragma unroll
    for (int r = 0; r < 16; ++r) ms[r] = 0.f;

    for (int s = 0; s < 32; ++s) {
        const short* sb = st[(s + 1) & 1];
        const bool pf = (s < 31);

        // 1) issue next-tile global loads (latency covered by MFMA phase)
        if (pf) STAGE_ISSUE(yp + (size_t)(b * 32 + s + 1) * 16 * 16384);

        // 2) MFMA phase
        f32x16 acc = ox;
        #pragma unroll
        for (int sh = 0; sh < 9; ++sh) {
            const int off = (sh / 3) * ROWP + (sh % 3) * CIP;
            acc = __builtin_amdgcn_mfma_f32_32x32x16_bf16(wy[sh], *(const short8*)&sb[cb + off], acc, 0, 0, 0);
        }

        // 3) pack + ds_write next tile
        if (pf) STAGE_WRITE(st[s & 1]);

        // 4) leaky + NT stores issued LAST — not drained at the barrier
        {
            float* p0 = inter + ((size_t)(b * 32 + s) * 64 + co0w + 4 * hi) * 16384
                      + (size_t)h * 128 + pxg * 32 + l31;
            #pragma unroll
            for (int r = 0; r < 16; ++r) {
                float v = acc[r];
                v = v >= 0.f ? v : NEG_SLOPE * v;
                __builtin_nontemporal_store(v, p0 + (ptrdiff_t)((r & 3) + 8 * (r >> 2)) * 16384);
                ms[r] += v;
            }
        }

        // 5) LDS-only barrier: wait ds ops, NOT the global stores
        asm volatile("s_waitcnt lgkmcnt(0)" ::: "memory");
        __builtin_amdgcn_s_barrier();
        asm volatile("" ::: "memory");
    }

    // ---------------- mean over Sy ----------------------------------------
    {
        float* p0 = ntgt + ((size_t)b * 64 + co0w + 4 * hi) * 16384
                  + (size_t)h * 128 + pxg * 32 + l31;
        #pragma unroll
        for (int r = 0; r < 16; ++r)
            __builtin_nontemporal_store(ms[r] * 0.03125f,
                                        p0 + (ptrdiff_t)((r & 3) + 8 * (r >> 2)) * 16384);
    }
#undef STAGE_ISSUE
#undef STAGE_WRITE
}

extern "C" void kernel_launch(void* const* d_in, const int* in_sizes, int n_in,
                              void* d_out, int out_size, void* d_ws, size_t ws_size,
                              hipStream_t stream) {
    const float* x    = (const float*)d_in[0];
    const float* y    = (const float*)d_in[1];
    const float* wgt  = (const float*)d_in[2];
    const float* bias = (const float*)d_in[3];
    float* out = (float*)d_out;

    crossop_mfma32<<<512, 512, 0, stream>>>(x, y, wgt, bias, out);
}